// Round 1
// baseline (138.187 us; speedup 1.0000x reference)
//
#include <hip/hip_runtime.h>
#include <hip/hip_bf16.h>

#define TDEPTH 6
#define NLEAF 64
#define NGATE 63
#define INF 512
#define OUTF 512
#define BATCH 1024

#define BM 128
#define BN 128
#define SPLITK 8
#define KCH 513   // 512 real i-chunks + 1 virtual chunk (x==1) for the pb bias term

typedef __attribute__((ext_vector_type(4))) float f32x4;
typedef __attribute__((ext_vector_type(2))) __bf16 bf16x2;
typedef __attribute__((ext_vector_type(4))) __bf16 bf16x4;
typedef __attribute__((ext_vector_type(8))) __bf16 bf16x8;

// ---------------- kernel 1: leaf probabilities ----------------
// leaf[b][l] = prod over depth d of (bit(l,d)==0 ? g[node] : 1-g[node]),
// g = sigmoid(x @ gw + gb)
__global__ __launch_bounds__(256) void leaf_kernel(
    const float* __restrict__ x, const float* __restrict__ gw,
    const float* __restrict__ gb, float* __restrict__ leaf) {
  const int wid = threadIdx.x >> 6, lane = threadIdx.x & 63;
  const int b = blockIdx.x * 4 + wid;
  __shared__ float g[4][NLEAF];
  if (lane < NGATE) {
    const float* xr = x + (size_t)b * INF;
    float a0 = 0.f, a1 = 0.f, a2 = 0.f, a3 = 0.f;
    #pragma unroll 4
    for (int i = 0; i < INF; i += 4) {
      a0 += xr[i + 0] * gw[(i + 0) * NGATE + lane];
      a1 += xr[i + 1] * gw[(i + 1) * NGATE + lane];
      a2 += xr[i + 2] * gw[(i + 2) * NGATE + lane];
      a3 += xr[i + 3] * gw[(i + 3) * NGATE + lane];
    }
    float t = (a0 + a1) + (a2 + a3) + gb[lane];
    g[wid][lane] = 1.0f / (1.0f + __expf(-t));
  }
  __syncthreads();
  float p = 1.0f;
  #pragma unroll
  for (int d = 0; d < TDEPTH; d++) {
    int prefix = lane >> (TDEPTH - 1 - d);        // top d+1 bits of leaf index
    int node = (1 << d) - 1 + (prefix >> 1);      // global gate index
    float gv = g[wid][node];
    p *= (prefix & 1) ? (1.0f - gv) : gv;         // bit 0 -> g, bit 1 -> 1-g
  }
  leaf[(size_t)b * NLEAF + lane] = p;
}

// ---------------- kernel 2: fused GEMM ----------------
// out_partial[s][b][o] = sum over this block's K-slice of A[b,k]*W[k,o]
// A[b, i*64+l] = x[b,i] * leaf[b,l]  (i==512 virtual: x==1)
// W as B^T: row o, col k=i*64+l  == pw[o][i][l] flat; i==512 chunk == pb[o][l]
__global__ __launch_bounds__(256) void gemm_kernel(
    const float* __restrict__ x, const float* __restrict__ pw,
    const float* __restrict__ pb, const float* __restrict__ leaf,
    float* __restrict__ partial) {
  __shared__ float leaf_lds[BM][NLEAF];   // 32 KB
  __shared__ float xsm[BM][8];            // 4 KB
  __shared__ __bf16 Asm[BM * NLEAF];      // 16 KB, XOR-swizzled rows of 128 B
  __shared__ __bf16 Bsm[BN * NLEAF];      // 16 KB, XOR-swizzled rows of 128 B

  const int tid = threadIdx.x;
  const int lane = tid & 63;
  const int wid = tid >> 6;
  const int bid = blockIdx.x;
  const int s  = bid & (SPLITK - 1);
  const int nb = (bid >> 3) & 3;
  const int mb = bid >> 5;
  const int m0 = mb * BM, n0 = nb * BN;
  const int cs = (s * KCH) / SPLITK;
  const int ce = ((s + 1) * KCH) / SPLITK;

  // stage leaf block (128 rows x 64 f32), fully coalesced
  {
    const float* src = leaf + (size_t)m0 * NLEAF;
    #pragma unroll
    for (int it = 0; it < 8; it++) {
      int e = (it * 256 + tid) * 4;
      *(f32x4*)(&leaf_lds[0][0] + e) = *(const f32x4*)(src + e);
    }
  }

  f32x4 acc[4][4];
  #pragma unroll
  for (int mi = 0; mi < 4; mi++)
    #pragma unroll
    for (int ni = 0; ni < 4; ni++) acc[mi][ni] = (f32x4){0.f, 0.f, 0.f, 0.f};

  const int wm = wid >> 1, wn = wid & 1;   // 2x2 wave grid, 64x64 per wave
  const int q = lane >> 4, rl = lane & 15;

  // A-gen assignment: thread -> (16-row group, col pair); row uniform per iter
  const int al2 = (tid & 31) * 2;
  const int rg16 = (tid >> 5) * 16;
  // B-stage assignment: thread -> (row n, 32-col half)
  const int bn = tid >> 1, bch = tid & 1;

  for (int ci = cs; ci < ce; ++ci) {
    __syncthreads();  // protect LDS tiles (and xsm) from previous iteration's reads

    if ((ci & 7) == 0 || ci == cs) {
      // stage x chunk: rows m0..m0+127, i in [i0, i0+8)
      int i0 = ci & ~7;
      int r = tid >> 1, c4 = (tid & 1) * 4;
      f32x4 v;
      if (i0 < INF) v = *(const f32x4*)(x + (size_t)(m0 + r) * INF + i0 + c4);
      else          v = (f32x4){1.f, 1.f, 1.f, 1.f};  // virtual bias chunk
      *(f32x4*)(&xsm[r][c4]) = v;
      __syncthreads();
    }
    const int i = ci;

    // B global loads first (let them fly while A-gen runs)
    const float* bsrc = (i < INF)
        ? (pw + (size_t)(n0 + bn) * (INF * NLEAF) + (size_t)i * NLEAF + bch * 32)
        : (pb + (size_t)(n0 + bn) * NLEAF + bch * 32);
    f32x4 bv[8];
    #pragma unroll
    for (int f = 0; f < 8; f++) bv[f] = *(const f32x4*)(bsrc + f * 4);

    // A-gen: A[r][l] = x[r][i] * leaf[r][l] -> bf16, swizzled LDS
    {
      const int isel = i & 7;
      #pragma unroll
      for (int rr = 0; rr < 16; rr++) {
        int r = rg16 + rr;
        float xv = xsm[r][isel];                 // wave-uniform broadcast
        float p0 = xv * leaf_lds[r][al2];
        float p1 = xv * leaf_lds[r][al2 + 1];
        bf16x2 pk; pk[0] = (__bf16)p0; pk[1] = (__bf16)p1;
        int byte = r * 128 + ((al2 * 2) ^ ((r & 7) << 4));
        *(bf16x2*)((char*)Asm + byte) = pk;
      }
    }

    // B convert + swizzled LDS write
    #pragma unroll
    for (int f = 0; f < 8; f++) {
      bf16x4 pk;
      pk[0] = (__bf16)bv[f][0]; pk[1] = (__bf16)bv[f][1];
      pk[2] = (__bf16)bv[f][2]; pk[3] = (__bf16)bv[f][3];
      int cbyte = (bch * 32 + f * 4) * 2;
      int byte = bn * 128 + (cbyte ^ ((bn & 7) << 4));
      *(bf16x4*)((char*)Bsm + byte) = pk;
    }

    __syncthreads();

    // fragments + MFMA: per wave 2(kk) x 4(mi) x 4(ni) = 32 MFMAs
    #pragma unroll
    for (int kk = 0; kk < 2; kk++) {
      bf16x8 af[4], bf[4];
      #pragma unroll
      for (int mi = 0; mi < 4; mi++) {
        int r = wm * 64 + mi * 16 + rl;
        int byte = r * 128 + ((kk * 64 + q * 16) ^ ((r & 7) << 4));
        af[mi] = *(const bf16x8*)((const char*)Asm + byte);
      }
      #pragma unroll
      for (int ni = 0; ni < 4; ni++) {
        int r = wn * 64 + ni * 16 + rl;
        int byte = r * 128 + ((kk * 64 + q * 16) ^ ((r & 7) << 4));
        bf[ni] = *(const bf16x8*)((const char*)Bsm + byte);
      }
      #pragma unroll
      for (int mi = 0; mi < 4; mi++)
        #pragma unroll
        for (int ni = 0; ni < 4; ni++)
          acc[mi][ni] = __builtin_amdgcn_mfma_f32_16x16x32_bf16(
              af[mi], bf[ni], acc[mi][ni], 0, 0, 0);
    }
  }

  // epilogue: partial[s][m0+row][n0+col]
  float* dst = partial + ((size_t)s * BATCH + m0) * OUTF + n0;
  #pragma unroll
  for (int mi = 0; mi < 4; mi++)
    #pragma unroll
    for (int ni = 0; ni < 4; ni++)
      #pragma unroll
      for (int r = 0; r < 4; r++) {
        int row = wm * 64 + mi * 16 + q * 4 + r;   // D row = (lane>>4)*4 + reg (m89)
        int col = wn * 64 + ni * 16 + rl;          // D col = lane&15
        dst[(size_t)row * OUTF + col] = acc[mi][ni][r];
      }
}

// ---------------- kernel 3: split-K reduce ----------------
__global__ __launch_bounds__(256) void reduce_kernel(
    const float* __restrict__ partial, float* __restrict__ out) {
  size_t e = ((size_t)blockIdx.x * 256 + threadIdx.x) * 4;
  f32x4 sum = (f32x4){0.f, 0.f, 0.f, 0.f};
  #pragma unroll
  for (int s = 0; s < SPLITK; s++)
    sum += *(const f32x4*)(partial + (size_t)s * BATCH * OUTF + e);
  *(f32x4*)(out + e) = sum;
}

extern "C" void kernel_launch(void* const* d_in, const int* in_sizes, int n_in,
                              void* d_out, int out_size, void* d_ws, size_t ws_size,
                              hipStream_t stream) {
  const float* x  = (const float*)d_in[0];
  const float* gw = (const float*)d_in[1];
  const float* gb = (const float*)d_in[2];
  const float* pw = (const float*)d_in[3];
  const float* pb = (const float*)d_in[4];
  float* out = (float*)d_out;

  float* leaf    = (float*)d_ws;                       // 1024*64*4 = 256 KB
  float* partial = (float*)((char*)d_ws + (1 << 20));  // 8*1024*512*4 = 16 MB

  leaf_kernel<<<BATCH / 4, 256, 0, stream>>>(x, gw, gb, leaf);
  gemm_kernel<<<(BATCH / BM) * (OUTF / BN) * SPLITK, 256, 0, stream>>>(
      x, pw, pb, leaf, partial);
  reduce_kernel<<<(BATCH * OUTF) / (256 * 4), 256, 0, stream>>>(partial, out);
}